// Round 15
// baseline (28.744 us; speedup 1.0000x reference)
//
#include <hip/hip_runtime.h>

namespace {

constexpr int kC = 20;
constexpr int kN = 8;
constexpr int kBS = 16384;
constexpr int kCells = kBS * 49;        // 802816
constexpr int kCT = 32;                 // cells per wave-tile (pair-split)
constexpr int kNT = kCells / kCT;       // 25088 wave-tiles
constexpr int kWaves = 5120;            // 20 waves/CU x 256 CUs
constexpr int kGrid = kWaves / 2;       // 2560 blocks x 128 threads
constexpr float kLC = 5.0f;
constexpr float kLN = 0.5f;
constexpr float kEps = 1e-6f;

typedef const __attribute__((address_space(1))) unsigned int gu32;
typedef __attribute__((address_space(3))) unsigned int lu32;

// Stage one 32-cell wave-tile (3840 B): 3 full 1 KB DMAs + 768 B (lanes<48).
// 4 vmcnt increments per stage.
__device__ __forceinline__ void stage(const float* __restrict__ outputs,
                                      int t, float* dst, int lane) {
  const char* srcb =
      reinterpret_cast<const char*>(outputs) + (size_t)t * (kCT * 120);
  char* dstb = reinterpret_cast<char*>(dst);
#pragma unroll
  for (int k = 0; k < 3; ++k) {
    __builtin_amdgcn_global_load_lds((gu32*)(srcb + k * 1024 + lane * 16),
                                     (lu32*)(dstb + k * 1024 + lane * 16),
                                     16, 0, 0);
  }
  if (lane < 48) {
    __builtin_amdgcn_global_load_lds((gu32*)(srcb + 3072 + lane * 16),
                                     (lu32*)(dstb + 3072 + lane * 16),
                                     16, 0, 0);
  }
}

__global__ __launch_bounds__(128) void yolo_loss_kernel(
    const float* __restrict__ outputs,   // [BS,7,7,30]
    const float* __restrict__ gt_boxes,  // [BS,8,4]
    const int* __restrict__ gt_labels,   // [BS,8]
    float* __restrict__ partials) {      // [kWaves]
  __shared__ float lds[2][2][kCT * 30];  // [wave][buf][960] = 15,360 B

  const int tid = threadIdx.x;
  const int lane = tid & 63;
  const int wv = tid >> 6;               // wave in block (independent)
  const int gw = blockIdx.x * 2 + wv;    // global wave id
  const int ci = lane >> 1;              // cell index within tile (0..31)
  const int b = lane & 1;                // box handled by this lane

  float acc = 0.0f;
  int t = gw;
  int cur = 0;
  stage(outputs, t, lds[wv][0], lane);   // prologue: 4 DMAs in flight

  while (true) {
    const int nxt = t + kWaves;
    const bool more = nxt < kNT;

    // ---- gt loads (8 box float4 + this lane's label int4); overlap DMA ----
    const int c = t * kCT + ci;
    const int bs = c / 49;               // pair lanes share bs
    float g[kN][4];
    const float4* gb4 =
        reinterpret_cast<const float4*>(gt_boxes + (size_t)bs * kN * 4);
#pragma unroll
    for (int n = 0; n < kN; ++n) {
      float4 v = gb4[n];
      g[n][0] = v.x; g[n][1] = v.y; g[n][2] = v.z; g[n][3] = v.w;
    }
    const int4 labA =
        reinterpret_cast<const int4*>(gt_labels + (size_t)bs * kN)[b];

    // ---- prefetch next tile into the other buffer (counted, not drained) ----
    if (more) {
      asm volatile("s_waitcnt lgkmcnt(0)" ::: "memory");  // old ds_reads done
      stage(outputs, nxt, lds[wv][cur ^ 1], lane);
    }

    // ---- gt-derived math (overlaps DMA flight) ----
    float gx1[kN], gx2[kN], gy1[kN], gy2[kN], ga[kN];
#pragma unroll
    for (int n = 0; n < kN; ++n) {
      gx1[n] = g[n][0] - g[n][2] * 0.5f;
      gx2[n] = g[n][0] + g[n][2] * 0.5f;
      gy1[n] = g[n][1] - g[n][3] * 0.5f;
      gy2[n] = g[n][1] + g[n][3] * 0.5f;
      ga[n]  = g[n][2] * g[n][3];
    }

    // ---- wait tile t's DMA + gt loads; leave the 4 prefetch in flight ----
    if (more) {
      asm volatile("s_waitcnt vmcnt(4)" ::: "memory");
    } else {
      asm volatile("s_waitcnt vmcnt(0)" ::: "memory");
    }

    const float* x = &lds[wv][cur][ci * 30];

    // ---- own box (5 words) ----
    const float* wb = x + b * 5;
    const float o0 = wb[0], o1 = wb[1], o2 = wb[2], o3 = wb[3], o4 = wb[4];
    const float px1 = o0 - o2 * 0.5f, px2 = o0 + o2 * 0.5f;
    const float py1 = o1 - o3 * 0.5f, py2 = o1 + o3 * 0.5f;
    const float pa = o2 * o3;

    // ---- 8 IOUs for own box (v_rcp: ~1ulp, threshold is 5.56) ----
    float iouv[kN];
#pragma unroll
    for (int n = 0; n < kN; ++n) {
      const float iw = fmaxf(fminf(px2, gx2[n]) - fmaxf(px1, gx1[n]), 0.0f);
      const float ih = fmaxf(fminf(py2, gy2[n]) - fmaxf(py1, gy1[n]), 0.0f);
      const float inter = iw * ih;
      iouv[n] = inter * __builtin_amdgcn_rcpf(pa + ga[n] - inter + kEps);
    }

    // ---- argmax scan with pair exchange (first-max wins = jnp.argmax) ----
    float best = -1.0f, i0j = 0.0f, i1j = 0.0f;
#pragma unroll
    for (int n = 0; n < kN; ++n) {
      const float other = __shfl_xor(iouv[n], 1, 64);
      const float i0 = b ? other : iouv[n];
      const float i1 = b ? iouv[n] : other;
      const float m = fmaxf(i0, i1);
      if (m > best) { best = m; i0j = i0; i1j = i1; }
    }
    const int bb = (i1j > i0j) ? 1 : 0;   // index 0 wins ties

    // ---- partner's box words; select chosen box ----
    const float q0 = __shfl_xor(o0, 1, 64), q1 = __shfl_xor(o1, 1, 64),
                q2 = __shfl_xor(o2, 1, 64), q3 = __shfl_xor(o3, 1, 64),
                q4 = __shfl_xor(o4, 1, 64);
    const bool own_chosen = (bb == b);
    const float psx = own_chosen ? o0 : q0;
    const float psy = own_chosen ? o1 : q1;
    const float psw = own_chosen ? o2 : q2;
    const float psh = own_chosen ? o3 : q3;
    const float psc = own_chosen ? o4 : q4;

    // ---- loc + conf (reference quirk: best_b indexes gt_boxes' N axis) ----
    const float gsx = bb ? g[1][0] : g[0][0];
    const float gsy = bb ? g[1][1] : g[0][1];
    const float sgw = __builtin_amdgcn_sqrtf(bb ? g[1][2] : g[0][2]);
    const float sgh = __builtin_amdgcn_sqrtf(bb ? g[1][3] : g[0][3]);
    const float dx = psx - gsx;
    const float dy = psy - gsy;
    const float dw = __builtin_amdgcn_sqrtf(psw) - sgw;
    const float dh = __builtin_amdgcn_sqrtf(psh) - sgh;
    const float loc = kLC * (dx * dx + dy * dy + dw * dw + dh * dh);
    const float conf_obj = (psc - best) * (psc - best);

    // ---- LSE: each lane exps its 10 classes, pair-combine (inputs in
    //      [0,1): no max pass needed) ----
    const float2* cp = reinterpret_cast<const float2*>(x + 10 + b * 10);
    float s0 = 0.0f, s1 = 0.0f;
#pragma unroll
    for (int j = 0; j < 5; ++j) {
      const float2 v = cp[j];
      s0 += __expf(v.x);
      s1 += __expf(v.y);
    }
    const float seh = s0 + s1;
    const float lse = __logf(seh + __shfl_xor(seh, 1, 64));

    // ---- CE: each lane gathers its 4 labels, pair-combine ----
    const float s4 =
        x[10 + labA.x] + x[10 + labA.y] + x[10 + labA.z] + x[10 + labA.w];
    const float s8 = s4 + __shfl_xor(s4, 1, 64);
    const float ce = lse - 0.125f * s8;   // == -(s8 - 8*lse)/8

    // ---- noobj (own conf + partner conf) ----
    const float noobj = kLN * (o4 * o4 + q4 * q4);

    const float val = (best > 0.0f) ? (loc + conf_obj + ce) : noobj;
    if (b == 0) acc += val;               // one contribution per cell

    if (!more) break;
    t = nxt;
    cur ^= 1;
  }

  // ---- wave reduction; one partial per wave (no barrier anywhere) ----
#pragma unroll
  for (int off = 32; off > 0; off >>= 1) acc += __shfl_down(acc, off, 64);
  if (lane == 0) partials[gw] = acc;
}

__global__ __launch_bounds__(256) void reduce_kernel(
    const float* __restrict__ partials, float* __restrict__ out) {
  // 5120 floats = 1280 float4; 256 threads -> 5 rounds
  const float4* p4 = reinterpret_cast<const float4*>(partials);
  float s = 0.0f;
  for (int i = threadIdx.x; i < kWaves / 4; i += 256) {
    const float4 v = p4[i];
    s += (v.x + v.y) + (v.z + v.w);
  }
#pragma unroll
  for (int off = 32; off > 0; off >>= 1) s += __shfl_down(s, off, 64);
  __shared__ float ws[4];
  const int lane = threadIdx.x & 63;
  const int wid = threadIdx.x >> 6;
  if (lane == 0) ws[wid] = s;
  __syncthreads();
  if (threadIdx.x == 0) {
    out[0] = (ws[0] + ws[1] + ws[2] + ws[3]) * (1.0f / kBS);  // exact 2^-14
  }
}

}  // namespace

extern "C" void kernel_launch(void* const* d_in, const int* in_sizes, int n_in,
                              void* d_out, int out_size, void* d_ws, size_t ws_size,
                              hipStream_t stream) {
  const float* outputs = (const float*)d_in[0];
  const float* gt_boxes = (const float*)d_in[1];
  const int* gt_labels = (const int*)d_in[2];
  float* out = (float*)d_out;
  float* partials = (float*)d_ws;   // kWaves floats = 20 KB, 16B-aligned

  yolo_loss_kernel<<<kGrid, 128, 0, stream>>>(outputs, gt_boxes, gt_labels, partials);
  reduce_kernel<<<1, 256, 0, stream>>>(partials, out);
}

// Round 16
// 28.507 us; speedup vs baseline: 1.0083x; 1.0083x over previous
//
#include <hip/hip_runtime.h>

namespace {

constexpr int kC = 20;
constexpr int kN = 8;
constexpr int kBS = 16384;
constexpr int kCells = kBS * 49;        // 802816
constexpr int kCT = 32;                 // cells per wave-tile (pair-split)
constexpr int kNT = kCells / kCT;       // 25088 wave-tiles
constexpr int kWaves = 8192;            // 32 waves/CU x 256 CUs (HW cap)
constexpr int kGrid = kWaves / 4;       // 2048 blocks x 256 threads
constexpr float kLC = 5.0f;
constexpr float kLN = 0.5f;
constexpr float kEps = 1e-6f;

typedef const __attribute__((address_space(1))) unsigned int gu32;
typedef __attribute__((address_space(3))) unsigned int lu32;

// Stage one 32-cell wave-tile (3840 B): 3 full 1 KB DMAs + 768 B (lanes<48).
__device__ __forceinline__ void stage(const float* __restrict__ outputs,
                                      int t, float* dst, int lane) {
  const char* srcb =
      reinterpret_cast<const char*>(outputs) + (size_t)t * (kCT * 120);
  char* dstb = reinterpret_cast<char*>(dst);
#pragma unroll
  for (int k = 0; k < 3; ++k) {
    __builtin_amdgcn_global_load_lds((gu32*)(srcb + k * 1024 + lane * 16),
                                     (lu32*)(dstb + k * 1024 + lane * 16),
                                     16, 0, 0);
  }
  if (lane < 48) {
    __builtin_amdgcn_global_load_lds((gu32*)(srcb + 3072 + lane * 16),
                                     (lu32*)(dstb + 3072 + lane * 16),
                                     16, 0, 0);
  }
}

__global__ __launch_bounds__(256) void yolo_loss_kernel(
    const float* __restrict__ outputs,   // [BS,7,7,30]
    const float* __restrict__ gt_boxes,  // [BS,8,4]
    const int* __restrict__ gt_labels,   // [BS,8]
    float* __restrict__ partials) {      // [kWaves]
  __shared__ float lds[4][kCT * 30];     // 4 waves x 3.84 KB = 15.36 KB

  const int tid = threadIdx.x;
  const int lane = tid & 63;
  const int wv = tid >> 6;               // wave in block (independent)
  const int gw = blockIdx.x * 4 + wv;    // global wave id (0..8191)
  const int ci = lane >> 1;              // cell index within tile (0..31)
  const int b = lane & 1;                // box handled by this lane

  float acc = 0.0f;

  // Persistent depth-1 loop: single buffer, wave-private, no barriers.
  for (int t = gw; t < kNT; t += kWaves) {
    // previous iteration's ds_reads must finish before DMA overwrites
    asm volatile("s_waitcnt lgkmcnt(0)" ::: "memory");
    stage(outputs, t, lds[wv], lane);

    // ---- gt loads (overlap DMA flight) ----
    const int c = t * kCT + ci;
    const int bs = c / 49;               // pair lanes share bs
    float g[kN][4];
    const float4* gb4 =
        reinterpret_cast<const float4*>(gt_boxes + (size_t)bs * kN * 4);
#pragma unroll
    for (int n = 0; n < kN; ++n) {
      float4 v = gb4[n];
      g[n][0] = v.x; g[n][1] = v.y; g[n][2] = v.z; g[n][3] = v.w;
    }
    const int4 labA =
        reinterpret_cast<const int4*>(gt_labels + (size_t)bs * kN)[b];

    // ---- gt-derived math (overlaps DMA flight) ----
    float gx1[kN], gx2[kN], gy1[kN], gy2[kN], ga[kN];
#pragma unroll
    for (int n = 0; n < kN; ++n) {
      gx1[n] = g[n][0] - g[n][2] * 0.5f;
      gx2[n] = g[n][0] + g[n][2] * 0.5f;
      gy1[n] = g[n][1] - g[n][3] * 0.5f;
      gy2[n] = g[n][1] + g[n][3] * 0.5f;
      ga[n]  = g[n][2] * g[n][3];
    }

    // ---- drain DMA + gt loads ----
    asm volatile("s_waitcnt vmcnt(0)" ::: "memory");

    const float* x = &lds[wv][ci * 30];

    // ---- own box (5 words) ----
    const float* wb = x + b * 5;
    const float o0 = wb[0], o1 = wb[1], o2 = wb[2], o3 = wb[3], o4 = wb[4];
    const float px1 = o0 - o2 * 0.5f, px2 = o0 + o2 * 0.5f;
    const float py1 = o1 - o3 * 0.5f, py2 = o1 + o3 * 0.5f;
    const float pa = o2 * o3;

    // ---- 8 IOUs for own box (v_rcp: ~1ulp, threshold is 5.56) ----
    float iouv[kN];
#pragma unroll
    for (int n = 0; n < kN; ++n) {
      const float iw = fmaxf(fminf(px2, gx2[n]) - fmaxf(px1, gx1[n]), 0.0f);
      const float ih = fmaxf(fminf(py2, gy2[n]) - fmaxf(py1, gy1[n]), 0.0f);
      const float inter = iw * ih;
      iouv[n] = inter * __builtin_amdgcn_rcpf(pa + ga[n] - inter + kEps);
    }

    // ---- argmax scan with pair exchange (first-max wins = jnp.argmax) ----
    float best = -1.0f, i0j = 0.0f, i1j = 0.0f;
#pragma unroll
    for (int n = 0; n < kN; ++n) {
      const float other = __shfl_xor(iouv[n], 1, 64);
      const float i0 = b ? other : iouv[n];
      const float i1 = b ? iouv[n] : other;
      const float m = fmaxf(i0, i1);
      if (m > best) { best = m; i0j = i0; i1j = i1; }
    }
    const int bb = (i1j > i0j) ? 1 : 0;   // index 0 wins ties

    // ---- partner's box words; select chosen box ----
    const float q0 = __shfl_xor(o0, 1, 64), q1 = __shfl_xor(o1, 1, 64),
                q2 = __shfl_xor(o2, 1, 64), q3 = __shfl_xor(o3, 1, 64),
                q4 = __shfl_xor(o4, 1, 64);
    const bool own_chosen = (bb == b);
    const float psx = own_chosen ? o0 : q0;
    const float psy = own_chosen ? o1 : q1;
    const float psw = own_chosen ? o2 : q2;
    const float psh = own_chosen ? o3 : q3;
    const float psc = own_chosen ? o4 : q4;

    // ---- loc + conf (reference quirk: best_b indexes gt_boxes' N axis) ----
    const float gsx = bb ? g[1][0] : g[0][0];
    const float gsy = bb ? g[1][1] : g[0][1];
    const float sgw = __builtin_amdgcn_sqrtf(bb ? g[1][2] : g[0][2]);
    const float sgh = __builtin_amdgcn_sqrtf(bb ? g[1][3] : g[0][3]);
    const float dx = psx - gsx;
    const float dy = psy - gsy;
    const float dw = __builtin_amdgcn_sqrtf(psw) - sgw;
    const float dh = __builtin_amdgcn_sqrtf(psh) - sgh;
    const float loc = kLC * (dx * dx + dy * dy + dw * dw + dh * dh);
    const float conf_obj = (psc - best) * (psc - best);

    // ---- LSE: each lane exps its 10 classes, pair-combine (inputs in
    //      [0,1): no max pass needed) ----
    const float2* cp = reinterpret_cast<const float2*>(x + 10 + b * 10);
    float s0 = 0.0f, s1 = 0.0f;
#pragma unroll
    for (int j = 0; j < 5; ++j) {
      const float2 v = cp[j];
      s0 += __expf(v.x);
      s1 += __expf(v.y);
    }
    const float seh = s0 + s1;
    const float lse = __logf(seh + __shfl_xor(seh, 1, 64));

    // ---- CE: each lane gathers its 4 labels, pair-combine ----
    const float s4 =
        x[10 + labA.x] + x[10 + labA.y] + x[10 + labA.z] + x[10 + labA.w];
    const float s8 = s4 + __shfl_xor(s4, 1, 64);
    const float ce = lse - 0.125f * s8;   // == -(s8 - 8*lse)/8

    // ---- noobj (own conf + partner conf) ----
    const float noobj = kLN * (o4 * o4 + q4 * q4);

    const float val = (best > 0.0f) ? (loc + conf_obj + ce) : noobj;
    if (b == 0) acc += val;               // one contribution per cell
  }

  // ---- wave reduction; one partial per wave (no barrier anywhere) ----
#pragma unroll
  for (int off = 32; off > 0; off >>= 1) acc += __shfl_down(acc, off, 64);
  if (lane == 0) partials[gw] = acc;
}

__global__ __launch_bounds__(256) void reduce_kernel(
    const float* __restrict__ partials, float* __restrict__ out) {
  // 8192 floats = 2048 float4; 256 threads -> 8 rounds
  const float4* p4 = reinterpret_cast<const float4*>(partials);
  float s = 0.0f;
  for (int i = threadIdx.x; i < kWaves / 4; i += 256) {
    const float4 v = p4[i];
    s += (v.x + v.y) + (v.z + v.w);
  }
#pragma unroll
  for (int off = 32; off > 0; off >>= 1) s += __shfl_down(s, off, 64);
  __shared__ float ws[4];
  const int lane = threadIdx.x & 63;
  const int wid = threadIdx.x >> 6;
  if (lane == 0) ws[wid] = s;
  __syncthreads();
  if (threadIdx.x == 0) {
    out[0] = (ws[0] + ws[1] + ws[2] + ws[3]) * (1.0f / kBS);  // exact 2^-14
  }
}

}  // namespace

extern "C" void kernel_launch(void* const* d_in, const int* in_sizes, int n_in,
                              void* d_out, int out_size, void* d_ws, size_t ws_size,
                              hipStream_t stream) {
  const float* outputs = (const float*)d_in[0];
  const float* gt_boxes = (const float*)d_in[1];
  const int* gt_labels = (const int*)d_in[2];
  float* out = (float*)d_out;
  float* partials = (float*)d_ws;   // kWaves floats = 32 KB, 16B-aligned

  yolo_loss_kernel<<<kGrid, 256, 0, stream>>>(outputs, gt_boxes, gt_labels, partials);
  reduce_kernel<<<1, 256, 0, stream>>>(partials, out);
}

// Round 17
// 25.466 us; speedup vs baseline: 1.1287x; 1.1194x over previous
//
#include <hip/hip_runtime.h>

namespace {

constexpr int kS = 7;
constexpr int kC = 20;
constexpr int kN = 8;
constexpr int kBS = 16384;
constexpr int kCells = kBS * kS * kS;   // 802816 = 3136 * 256
constexpr int kTile = 256;              // cells per tile (= block size)
constexpr int kNT = kCells / kTile;     // 3136 tiles
constexpr int kGrid = 1280;             // 5 blocks/CU exactly, all resident
constexpr int kF = 30;                  // floats per cell (120 B)
constexpr float kLambdaCoord = 5.0f;
constexpr float kLambdaNoobj = 0.5f;
constexpr float kEps = 1e-6f;

typedef const __attribute__((address_space(1))) unsigned int gu32;
typedef __attribute__((address_space(3))) unsigned int lu32;

__global__ __launch_bounds__(256) void yolo_loss_kernel(
    const float* __restrict__ outputs,   // [BS,7,7,30]
    const float* __restrict__ gt_boxes,  // [BS,8,4]
    const int* __restrict__ gt_labels,   // [BS,8]
    float* __restrict__ partials) {      // [kGrid]
  __shared__ float lds[kTile * kF];      // 30 KB transpose buffer
  __shared__ float ws[4];

  const int tid = threadIdx.x;
  const int lane = tid & 63;
  const int w = tid >> 6;                // wave id, uniform per wave

  float val = 0.0f;

  // Persistent loop: block b handles tiles b, b+1280, b+2560. Waves are
  // fully independent across iterations (wave-private LDS slices) -> NO
  // barrier in the loop; only wave-local waitcnt fences.
  for (int t = blockIdx.x; t < kNT; t += kGrid) {
    // Prior iteration's ds_reads must complete before the DMA may overwrite
    // this wave's slice (compiler cannot see the DMA->LDS dependence).
    asm volatile("s_waitcnt lgkmcnt(0)" ::: "memory");

    // ---- WAVE-PRIVATE async DMA stage: wave w stages its own 64 cells
    //      (7680 B) as 7 full 1 KB global_load_lds + 1 half (lanes 0-31).
    {
      const char* srcb = reinterpret_cast<const char*>(outputs) +
                         ((size_t)t * kTile + (size_t)w * 64) * 120;
      char* dstb = reinterpret_cast<char*>(lds) + w * 7680;
#pragma unroll
      for (int k = 0; k < 7; ++k) {
        __builtin_amdgcn_global_load_lds((gu32*)(srcb + k * 1024 + lane * 16),
                                         (lu32*)(dstb + k * 1024 + lane * 16),
                                         16, 0, 0);
      }
      if (lane < 32) {
        __builtin_amdgcn_global_load_lds((gu32*)(srcb + 7168 + lane * 16),
                                         (lu32*)(dstb + 7168 + lane * 16),
                                         16, 0, 0);
      }
    }

    // ---- gt loads issue now; latency overlaps the DMA ----
    const int c = t * kTile + tid;
    const int bs = c / (kS * kS);
    float g[kN][4];
    const float4* gb4 =
        reinterpret_cast<const float4*>(gt_boxes + (size_t)bs * kN * 4);
#pragma unroll
    for (int n = 0; n < kN; ++n) {
      float4 v = gb4[n];
      g[n][0] = v.x; g[n][1] = v.y; g[n][2] = v.z; g[n][3] = v.w;
    }
    const int4* lb4 = reinterpret_cast<const int4*>(gt_labels + (size_t)bs * kN);
    const int4 lab0 = lb4[0];
    const int4 lab1 = lb4[1];

    // ---- precompute gt corners/areas once (overlaps DMA flight) ----
    float gx1[kN], gx2[kN], gy1[kN], gy2[kN], ga[kN];
#pragma unroll
    for (int n = 0; n < kN; ++n) {
      gx1[n] = g[n][0] - g[n][2] * 0.5f;
      gx2[n] = g[n][0] + g[n][2] * 0.5f;
      gy1[n] = g[n][1] - g[n][3] * 0.5f;
      gy2[n] = g[n][1] + g[n][3] * 0.5f;
      ga[n]  = g[n][2] * g[n][3];
    }

    // ---- wave-local drain of the DMA (also covers gt loads) ----
    asm volatile("s_waitcnt vmcnt(0)" ::: "memory");

    // per-thread cell in LDS; word-stride 30 across lanes
    const float* x = lds + tid * kF;

    // ---- pairwise IOU (v_rcp_f32: ~1ulp, far below the 5.56 threshold) ----
    float iou[2][kN];
#pragma unroll
    for (int b = 0; b < 2; ++b) {
      const float px = x[b * 5 + 0], py = x[b * 5 + 1];
      const float pw = x[b * 5 + 2], ph = x[b * 5 + 3];
      const float px1 = px - pw * 0.5f, px2 = px + pw * 0.5f;
      const float py1 = py - ph * 0.5f, py2 = py + ph * 0.5f;
      const float parea = pw * ph;
#pragma unroll
      for (int n = 0; n < kN; ++n) {
        const float iw = fmaxf(fminf(px2, gx2[n]) - fmaxf(px1, gx1[n]), 0.0f);
        const float ih = fmaxf(fminf(py2, gy2[n]) - fmaxf(py1, gy1[n]), 0.0f);
        const float inter = iw * ih;
        const float uni = parea + ga[n] - inter;
        iou[b][n] = inter * __builtin_amdgcn_rcpf(uni + kEps);
      }
    }

    // ---- j_star scan (first-max wins, matches jnp.argmax) ----
    float best_iou = -1.0f;
    float i0j = 0.0f, i1j = 0.0f;
#pragma unroll
    for (int n = 0; n < kN; ++n) {
      const float m = fmaxf(iou[0][n], iou[1][n]);
      if (m > best_iou) { best_iou = m; i0j = iou[0][n]; i1j = iou[1][n]; }
    }
    const int bb = (i1j > i0j) ? 1 : 0;   // index 0 wins ties

    // ---- selections (reference quirk: best_b indexes gt_boxes' N axis) ----
    const float gsx = bb ? g[1][0] : g[0][0];
    const float gsy = bb ? g[1][1] : g[0][1];
    const float gsw = bb ? g[1][2] : g[0][2];
    const float gsh = bb ? g[1][3] : g[0][3];
    const float psx = bb ? x[5] : x[0];
    const float psy = bb ? x[6] : x[1];
    const float psw = bb ? x[7] : x[2];
    const float psh = bb ? x[8] : x[3];
    const float psc = bb ? x[9] : x[4];

    // ---- localization + confidence (raw v_sqrt_f32: ~1ulp) ----
    const float dx = psx - gsx;
    const float dy = psy - gsy;
    const float dw = __builtin_amdgcn_sqrtf(psw) - __builtin_amdgcn_sqrtf(gsw);
    const float dh = __builtin_amdgcn_sqrtf(psh) - __builtin_amdgcn_sqrtf(gsh);
    const float loc = kLambdaCoord * (dx * dx + dy * dy + dw * dw + dh * dh);
    const float conf_obj = (psc - best_iou) * (psc - best_iou);

    // ---- log-sum-exp over 20 classes (inputs in [0,1): no max pass);
    //      4 accumulators shorten the dependence chain ----
    float se0 = 0.0f, se1 = 0.0f, se2 = 0.0f, se3 = 0.0f;
#pragma unroll
    for (int k = 0; k < kC; k += 4) {
      se0 += __expf(x[10 + k + 0]);
      se1 += __expf(x[10 + k + 1]);
      se2 += __expf(x[10 + k + 2]);
      se3 += __expf(x[10 + k + 3]);
    }
    const float lse = __logf((se0 + se1) + (se2 + se3));

    // ---- CE over the 8 labels (dynamic LDS gather) ----
    float s8 = 0.0f;
    s8 += x[10 + lab0.x] + x[10 + lab0.y] + x[10 + lab0.z] + x[10 + lab0.w];
    s8 += x[10 + lab1.x] + x[10 + lab1.y] + x[10 + lab1.z] + x[10 + lab1.w];
    const float ce = lse - 0.125f * s8;   // == -(s8 - 8*lse)/8

    // ---- noobj ----
    const float noobj = kLambdaNoobj * (x[4] * x[4] + x[9] * x[9]);

    val += (best_iou > 0.0f) ? (loc + conf_obj + ce) : noobj;
  }

  // ---- block reduction: wave64 shuffle, then LDS across the 4 waves ----
#pragma unroll
  for (int off = 32; off > 0; off >>= 1) val += __shfl_down(val, off, 64);
  if (lane == 0) ws[w] = val;
  __syncthreads();
  if (tid == 0) {
    partials[blockIdx.x] = ws[0] + ws[1] + ws[2] + ws[3];  // NO atomic
  }
}

__global__ __launch_bounds__(256) void reduce_kernel(
    const float* __restrict__ partials, float* __restrict__ out) {
  // 1280 floats = 320 float4; 256 threads -> 2 rounds
  const float4* p4 = reinterpret_cast<const float4*>(partials);
  float s = 0.0f;
  for (int i = threadIdx.x; i < kGrid / 4; i += 256) {
    const float4 v = p4[i];
    s += (v.x + v.y) + (v.z + v.w);
  }
#pragma unroll
  for (int off = 32; off > 0; off >>= 1) s += __shfl_down(s, off, 64);
  __shared__ float ws[4];
  const int lane = threadIdx.x & 63;
  const int wid = threadIdx.x >> 6;
  if (lane == 0) ws[wid] = s;
  __syncthreads();
  if (threadIdx.x == 0) {
    out[0] = (ws[0] + ws[1] + ws[2] + ws[3]) * (1.0f / kBS);  // exact 2^-14
  }
}

}  // namespace

extern "C" void kernel_launch(void* const* d_in, const int* in_sizes, int n_in,
                              void* d_out, int out_size, void* d_ws, size_t ws_size,
                              hipStream_t stream) {
  const float* outputs = (const float*)d_in[0];
  const float* gt_boxes = (const float*)d_in[1];
  const int* gt_labels = (const int*)d_in[2];
  float* out = (float*)d_out;
  float* partials = (float*)d_ws;   // kGrid floats = 5 KB, 16B-aligned

  yolo_loss_kernel<<<kGrid, kTile, 0, stream>>>(outputs, gt_boxes, gt_labels, partials);
  reduce_kernel<<<1, 256, 0, stream>>>(partials, out);
}